// Round 15
// baseline (85.375 us; speedup 1.0000x reference)
//
#include <hip/hip_runtime.h>

#define BB 32
#define HH 512
#define WW 512
#define CC 3
#define KK 16
#define NE 19          // K + 3
#define KNL 16         // nonlinear kernel terms (loaded from right_mat)
#define NN (HH * WW)   // 262144
#define BPB 16         // batches per block
#define NCOEFF (BPB * 2 * NE) // 608
// 2D output tiling: 32 wide x 8 tall per 256-thread block.
#define TLW 32
#define TLH 8
#define TILES_X (WW / TLW)  // 16
#define TILES_Y (HH / TLH)  // 64

typedef float v4f __attribute__((ext_vector_type(4)));
typedef float v2f __attribute__((ext_vector_type(2)));

// Volatile asm: issue order preserved among asm; results stay in flight.
#define ISSUE_ROW(q4, q2, addr)                                              \
    asm volatile("global_load_dwordx4 %0, %2, off\n\t"                       \
                 "global_load_dwordx2 %1, %2, off offset:16"                 \
                 : "=&v"(q4), "=&v"(q2)                                      \
                 : "v"(addr))

// Counted wait. "memory" clobber pins compiler-emitted stores into their
// inter-wait region so the hand-derived vmcnt counts below stay exact.
#define WAITN(NW, A4, A2, B4, B2)                                            \
    asm volatile("s_waitcnt vmcnt(" #NW ")"                                  \
                 : "+v"(A4), "+v"(A2), "+v"(B4), "+v"(B2) :: "memory")

__global__ __launch_bounds__(256, 4) void tps_kernel(
    const float* __restrict__ image,        // (B,H,W,C)
    const float* __restrict__ dest_offsets, // (B, 2K)
    const float* __restrict__ right_mat,    // (NE, N)
    const float* __restrict__ L_inv,        // (NE, NE)
    const float* __restrict__ src_pts,      // (2, K)
    float* __restrict__ out)                // (B,H,W,C)
{
    __shared__ float s_coeff[BPB][2][NE];
    const int tid = threadIdx.x;
    const int b0 = blockIdx.y * BPB;

    // TPS coefficients for this block's batch group.
    for (int i = tid; i < NCOEFF; i += 256) {
        const int bb = i / (2 * NE);
        const int rem = i - bb * (2 * NE);
        const int p = rem / NE;
        const int e = rem - p * NE;
        const int b = b0 + bb;
        float acc = 0.0f;
        #pragma unroll
        for (int k = 0; k < KK; ++k) {
            const float d = src_pts[p * KK + k] + dest_offsets[b * 2 * KK + p * KK + k];
            acc = fmaf(d, L_inv[e * NE + 3 + k], acc);
        }
        ((float*)s_coeff)[i] = acc;
    }
    __syncthreads();

    const int tix = blockIdx.x & (TILES_X - 1);
    const int tiy = blockIdx.x >> 4;
    const int col = tix * TLW + (tid & (TLW - 1));
    const int row = tiy * TLH + (tid >> 5);
    const int n = row * WW + col;

    const float xt = fmaf((float)col, 2.0f / 511.0f, -1.0f);
    const float yt = fmaf((float)row, 2.0f / 511.0f, -1.0f);

    // Nonlinear rows: exact precomputed values (r10 lesson). Consumed in
    // CI(0)'s FMA chain -> compiler drains them before our first asm issue.
    float rm[KNL];
    #pragma unroll
    for (int e = 0; e < KNL; ++e)
        rm[e] = right_mat[(size_t)(e + 3) * NN + n];

    float* __restrict__ o = out + (size_t)b0 * NN * CC + (size_t)n * CC;

    // Depth-4 software pipeline, rotating register slots (static indices).
    float wgt[4][4];
    bool hiA[4], hiC[4];
    v4f a4[4], b4[4];
    v2f a2[4], b2[4];

#define CI(bb) do {                                                          \
    const float* cf0 = s_coeff[bb][0];                                       \
    const float* cf1 = s_coeff[bb][1];                                       \
    float tx = fmaf(cf0[1], xt, cf0[0]);                                     \
    float ty = fmaf(cf1[1], xt, cf1[0]);                                     \
    tx = fmaf(cf0[2], yt, tx);                                               \
    ty = fmaf(cf1[2], yt, ty);                                               \
    _Pragma("unroll")                                                        \
    for (int k = 0; k < KNL; ++k) {                                          \
        tx = fmaf(cf0[3 + k], rm[k], tx);                                    \
        ty = fmaf(cf1[3 + k], rm[k], ty);                                    \
    }                                                                        \
    const float x = 0.5f * (tx + 1.0f) * (float)WW;                          \
    const float y = 0.5f * (ty + 1.0f) * (float)HH;                          \
    int x0 = (int)x;                                                         \
    int x1 = x0 + 1;                                                         \
    int y0 = (int)y;                                                         \
    int y1 = y0 + 1;                                                         \
    x0 = min(max(x0, 0), WW - 1);                                            \
    x1 = min(max(x1, 0), WW - 1);                                            \
    y0 = min(max(y0, 0), HH - 1);                                            \
    y1 = min(max(y1, 0), HH - 1);                                            \
    const float x0f = (float)x0, x1f = (float)x1;                            \
    const float y0f = (float)y0, y1f = (float)y1;                            \
    wgt[(bb)&3][0] = (x1f - x) * (y1f - y);                                  \
    wgt[(bb)&3][1] = (x1f - x) * (y - y0f);                                  \
    wgt[(bb)&3][2] = (x - x0f) * (y1f - y);                                  \
    wgt[(bb)&3][3] = (x - x0f) * (y - y0f);                                  \
    const int xs = min(x0, WW - 2);                                          \
    hiA[(bb)&3] = (x0 > xs);                                                 \
    hiC[(bb)&3] = (x1 > xs);                                                 \
    const float* img = image + (size_t)(b0 + (bb)) * NN * CC;                \
    const float* rowA = img + ((size_t)y0 * WW + xs) * CC;                   \
    const float* rowB = img + ((size_t)y1 * WW + xs) * CC;                   \
    ISSUE_ROW(a4[(bb)&3], a2[(bb)&3], rowA);                                 \
    ISSUE_ROW(b4[(bb)&3], b2[(bb)&3], rowB);                                 \
} while (0)

#define CONS(bb, NW) do {                                                    \
    WAITN(NW, a4[(bb)&3], a2[(bb)&3], b4[(bb)&3], b2[(bb)&3]);               \
    const float la[6] = { a4[(bb)&3].x, a4[(bb)&3].y, a4[(bb)&3].z,          \
                          a4[(bb)&3].w, a2[(bb)&3].x, a2[(bb)&3].y };        \
    const float lb[6] = { b4[(bb)&3].x, b4[(bb)&3].y, b4[(bb)&3].z,          \
                          b4[(bb)&3].w, b2[(bb)&3].x, b2[(bb)&3].y };        \
    float res[CC];                                                           \
    _Pragma("unroll")                                                        \
    for (int c = 0; c < CC; ++c) {                                           \
        const float pa = hiA[(bb)&3] ? la[c + 3] : la[c];                    \
        const float pc = hiC[(bb)&3] ? la[c + 3] : la[c];                    \
        const float pb = hiA[(bb)&3] ? lb[c + 3] : lb[c];                    \
        const float pd = hiC[(bb)&3] ? lb[c + 3] : lb[c];                    \
        res[c] = wgt[(bb)&3][0] * pa + wgt[(bb)&3][1] * pb                   \
               + wgt[(bb)&3][2] * pc + wgt[(bb)&3][3] * pd;                  \
    }                                                                        \
    __builtin_memcpy(o + (size_t)(bb) * NN * CC, res, CC * sizeof(float));   \
} while (0)

    // vmcnt counts (in-order retirement; L=4 loads/batch, S=1 store):
    // steady wait = 3 batches x 4 loads + 3 stores = 15; tail exact 11/7/3.
    CI(0); CI(1); CI(2); CI(3);
    CONS(0, 12); CI(4);
    CONS(1, 13); CI(5);
    CONS(2, 14); CI(6);
    CONS(3, 15); CI(7);
    CONS(4, 15); CI(8);
    CONS(5, 15); CI(9);
    CONS(6, 15); CI(10);
    CONS(7, 15); CI(11);
    CONS(8, 15); CI(12);
    CONS(9, 15); CI(13);
    CONS(10, 15); CI(14);
    CONS(11, 15); CI(15);
    CONS(12, 15);
    CONS(13, 11);
    CONS(14, 7);
    CONS(15, 3);

#undef CI
#undef CONS
}

extern "C" void kernel_launch(void* const* d_in, const int* in_sizes, int n_in,
                              void* d_out, int out_size, void* d_ws, size_t ws_size,
                              hipStream_t stream) {
    const float* image        = (const float*)d_in[0];
    const float* dest_offsets = (const float*)d_in[1];
    const float* right_mat    = (const float*)d_in[2];
    const float* L_inv        = (const float*)d_in[3];
    const float* src_pts      = (const float*)d_in[4];
    float* out = (float*)d_out;

    dim3 grid(TILES_X * TILES_Y, BB / BPB);
    dim3 block(256);
    hipLaunchKernelGGL(tps_kernel, grid, block, 0, stream,
                       image, dest_offsets, right_mat, L_inv, src_pts, out);
}

// Round 16
// 65.095 us; speedup vs baseline: 1.3116x; 1.3116x over previous
//
#include <hip/hip_runtime.h>

#define BB 32
#define HH 512
#define WW 512
#define CC 3
#define KK 16
#define NE 19          // K + 3
#define KNL 16         // nonlinear kernel terms (loaded from right_mat)
#define NN (HH * WW)   // 262144
#define BPB 16         // batches per block
#define NCOEFF (BPB * 2 * NE) // 608
// 2D output tiling: 32 wide x 8 tall per 256-thread block.
#define TLW 32
#define TLH 8
#define TILES_X (WW / TLW)  // 16
#define TILES_Y (HH / TLH)  // 64

__global__ __launch_bounds__(256, 4) void tps_kernel(
    const float* __restrict__ image,        // (B,H,W,C)
    const float* __restrict__ dest_offsets, // (B, 2K)
    const float* __restrict__ right_mat,    // (NE, N)
    const float* __restrict__ L_inv,        // (NE, NE)
    const float* __restrict__ src_pts,      // (2, K)
    float* __restrict__ out)                // (B,H,W,C)
{
    __shared__ float s_coeff[BPB][2][NE];
    const int tid = threadIdx.x;
    const int b0 = blockIdx.y * BPB;

    // TPS coefficients for this block's batch group:
    // coeff[bb][p][e] = sum_k (src[p][k] + off[b][p*K+k]) * L_inv[e][3+k]
    for (int i = tid; i < NCOEFF; i += 256) {
        const int bb = i / (2 * NE);
        const int rem = i - bb * (2 * NE);
        const int p = rem / NE;
        const int e = rem - p * NE;
        const int b = b0 + bb;
        float acc = 0.0f;
        #pragma unroll
        for (int k = 0; k < KK; ++k) {
            const float d = src_pts[p * KK + k] + dest_offsets[b * 2 * KK + p * KK + k];
            acc = fmaf(d, L_inv[e * NE + 3 + k], acc);
        }
        ((float*)s_coeff)[i] = acc;
    }
    __syncthreads();

    // 2D tile -> pixel: vertical y0/y1 gather reuse stays inside the block
    // (L1) instead of spanning blocks on different XCDs.
    const int tix = blockIdx.x & (TILES_X - 1);
    const int tiy = blockIdx.x >> 4;
    const int col = tix * TLW + (tid & (TLW - 1));
    const int row = tiy * TLH + (tid >> 5);
    const int n = row * WW + col;

    // Linear right_mat rows [1; x_t; y_t]: computed (verified r5-r7, r11-r13).
    const float xt = fmaf((float)col, 2.0f / 511.0f, -1.0f);
    const float yt = fmaf((float)row, 2.0f / 511.0f, -1.0f);

    // Nonlinear rows: MUST be the exact precomputed values (r10 lesson:
    // recomputing with logf flips pixels across the trunc/clip
    // discontinuity at the image border -> absmax blowup).
    float rm[KNL];
    #pragma unroll
    for (int e = 0; e < KNL; ++e)
        rm[e] = right_mat[(size_t)(e + 3) * NN + n];

    float* __restrict__ o = out + (size_t)b0 * NN * CC + (size_t)n * CC;

    #pragma unroll
    for (int bb = 0; bb < BPB; ++bb) {
        const float* cf0 = s_coeff[bb][0];
        const float* cf1 = s_coeff[bb][1];
        float tx = fmaf(cf0[1], xt, cf0[0]);
        float ty = fmaf(cf1[1], xt, cf1[0]);
        tx = fmaf(cf0[2], yt, tx);
        ty = fmaf(cf1[2], yt, ty);
        #pragma unroll
        for (int k = 0; k < KNL; ++k) {
            tx = fmaf(cf0[3 + k], rm[k], tx);
            ty = fmaf(cf1[3 + k], rm[k], ty);
        }

        const float x = 0.5f * (tx + 1.0f) * (float)WW;
        const float y = 0.5f * (ty + 1.0f) * (float)HH;

        int x0 = (int)x;   // trunc toward zero, matches astype(int32)
        int x1 = x0 + 1;
        int y0 = (int)y;
        int y1 = y0 + 1;
        x0 = min(max(x0, 0), WW - 1);
        x1 = min(max(x1, 0), WW - 1);
        y0 = min(max(y0, 0), HH - 1);
        y1 = min(max(y1, 0), HH - 1);

        const float x0f = (float)x0, x1f = (float)x1;
        const float y0f = (float)y0, y1f = (float)y1;
        const float wa = (x1f - x) * (y1f - y);
        const float wb = (x1f - x) * (y - y0f);
        const float wc = (x - x0f) * (y1f - y);
        const float wd = (x - x0f) * (y - y0f);

        // Row-pair gather: 6 contiguous floats per row from xs = min(x0, W-2).
        const int xs = min(x0, WW - 2);
        const bool hi_a = (x0 > xs);
        const bool hi_c = (x1 > xs);

        const float* img = image + (size_t)(b0 + bb) * NN * CC;
        const float* rowA = img + ((size_t)y0 * WW + xs) * CC;
        const float* rowB = img + ((size_t)y1 * WW + xs) * CC;
        float la[6], lb[6];
        __builtin_memcpy(la, rowA, 6 * sizeof(float));
        __builtin_memcpy(lb, rowB, 6 * sizeof(float));

        float res[CC];
        #pragma unroll
        for (int c = 0; c < CC; ++c) {
            const float pa = hi_a ? la[c + 3] : la[c];
            const float pc = hi_c ? la[c + 3] : la[c];
            const float pb = hi_a ? lb[c + 3] : lb[c];
            const float pd = hi_c ? lb[c + 3] : lb[c];
            res[c] = wa * pa + wb * pb + wc * pc + wd * pd;
        }
        __builtin_memcpy(o + (size_t)bb * NN * CC, res, CC * sizeof(float));
    }
}

extern "C" void kernel_launch(void* const* d_in, const int* in_sizes, int n_in,
                              void* d_out, int out_size, void* d_ws, size_t ws_size,
                              hipStream_t stream) {
    const float* image        = (const float*)d_in[0];
    const float* dest_offsets = (const float*)d_in[1];
    const float* right_mat    = (const float*)d_in[2];
    const float* L_inv        = (const float*)d_in[3];
    const float* src_pts      = (const float*)d_in[4];
    float* out = (float*)d_out;

    dim3 grid(TILES_X * TILES_Y, BB / BPB);
    dim3 block(256);
    hipLaunchKernelGGL(tps_kernel, grid, block, 0, stream,
                       image, dest_offsets, right_mat, L_inv, src_pts, out);
}